// Round 1
// baseline (267.335 us; speedup 1.0000x reference)
//
#include <hip/hip_runtime.h>

#define B_    16384
#define NZ_   64
#define ND_   8
#define SDIM_ 128
#define H_    512

typedef _Float16 f16;
typedef __attribute__((ext_vector_type(8))) _Float16 half8;
typedef __attribute__((ext_vector_type(4))) float floatx4;

// ---------------- async global->LDS, 16B per lane ----------------
__device__ __forceinline__ void gload16(const void* gp, void* lp) {
    void* g = const_cast<void*>(gp);
    __builtin_amdgcn_global_load_lds(
        (__attribute__((address_space(1))) void*)g,
        (__attribute__((address_space(3))) void*)lp, 16, 0, 0);
}

// ---------------- prep: f32->f16 convert (+transpose), zero counters ----------------
// transpose mode: src [batch][K][N] f32 -> dst [batch][N][K] f16
template<int K, int N, int BATCH, int MODE>
__device__ void cvt_body(const float* __restrict__ s, f16* __restrict__ d) {
    const int total  = K * N * BATCH;
    const int stride = gridDim.x * blockDim.x;
    for (int i = blockIdx.x * blockDim.x + threadIdx.x; i < total; i += stride) {
        if (MODE == 1) {
            d[i] = (f16)s[i];
        } else {
            int b   = i / (N * K);
            int rem = i - b * (N * K);
            int n   = rem / K;
            int k   = rem - n * K;
            d[i] = (f16)s[(size_t)b * K * N + (size_t)k * N + n];
        }
    }
}

__global__ __launch_bounds__(256) void prep_k(
    const float* W0, const float* W1, const float* W2, const float* W3,
    const float* U1, const float* U2, const float* U3, const float* Uo,
    const float* z,
    f16* W0t, f16* W1t, f16* W2t, f16* W3t,
    f16* U1t, f16* U2t, f16* U3t, f16* Uot, f16* zh,
    int* cnt, int* rowmap)
{
    switch (blockIdx.y) {
        case 0: cvt_body<64, 512, 1, 0>(W0, W0t); break;
        case 1: cvt_body<512, 512, 1, 0>(W1, W1t); break;
        case 2: cvt_body<512, 512, 1, 0>(W2, W2t); break;
        case 3: cvt_body<512, 512, 1, 0>(W3, W3t); break;
        case 4: cvt_body<512, 512, 8, 0>(U1, U1t); break;
        case 5: cvt_body<512, 512, 8, 0>(U2, U2t); break;
        case 6: cvt_body<512, 512, 8, 0>(U3, U3t); break;
        case 7: cvt_body<512, 128, 8, 0>(Uo, Uot); break;
        case 8: cvt_body<1, B_ * NZ_, 1, 1>(z, zh); break;
        case 9:
            if (blockIdx.x == 0) {
                int t = threadIdx.x;
                if (t < ND_) cnt[t] = 0;
                if (t < 128) rowmap[B_ + t] = 0;   // pad for last-domain tail tile
            }
            break;
        default: break;
    }
}

// ---------------- domain sort: count -> prefix -> scatter ----------------
__global__ __launch_bounds__(256) void count_k(const int* __restrict__ y,
                                               int* __restrict__ cnt,
                                               int* __restrict__ pos) {
    int b = blockIdx.x * 256 + threadIdx.x;   // grid exactly covers B_
    pos[b] = atomicAdd(&cnt[y[b]], 1);
}

__global__ void prefix_k(const int* __restrict__ cnt, int* __restrict__ offs,
                         int* __restrict__ ts) {
    if (threadIdx.x == 0) {
        int o = 0, tt = 0;
        offs[0] = 0; ts[0] = 0;
        for (int d = 0; d < ND_; d++) {
            o += cnt[d];              offs[d + 1] = o;
            tt += (cnt[d] + 127) >> 7; ts[d + 1] = tt;
        }
    }
}

__global__ __launch_bounds__(256) void scatter_k(const int* __restrict__ y,
                                                 const int* __restrict__ pos,
                                                 const int* __restrict__ offs,
                                                 int* __restrict__ rowmap) {
    int b = blockIdx.x * 256 + threadIdx.x;
    rowmap[offs[y[b]] + pos[b]] = b;
}

// ---------------- fused GEMM: C = act(A @ W + bias) ----------------
// A: [rows][K] f16 row-major.  Bt: weights TRANSPOSED [*, N][K] f16 (so B-frag
// reads are contiguous in K).  128x128 tile, 4 waves (2x2), BK=32, m97 structure.
// MODE 0: trunk  — dense rows, f16 out, relu
// MODE 1: branch — domain-tiled, f16 out (permuted buffer), relu, masked store
// MODE 2: branch+gather — as 1 but A rows via rowmap
// MODE 3: final  — domain-tiled, f32 scatter to d_out via rowmap, +bias, no relu
template<int MODE>
__global__ __launch_bounds__(256, 2) void gemm_k(
    const f16* __restrict__ A, const f16* __restrict__ Bt,
    const float* __restrict__ bias,
    f16* __restrict__ outh, float* __restrict__ outf,
    const int* __restrict__ offs, const int* __restrict__ cnt,
    const int* __restrict__ ts, const int* __restrict__ rowmap,
    int N, int K)
{
    __shared__ f16 sA[128 * 32];   // 8 KB, [row][k] chunks of 8 f16
    __shared__ f16 sB[128 * 32];   // 8 KB, [n][k]

    const int t  = threadIdx.x;
    const int bx = blockIdx.x, by = blockIdx.y;

    int row0, vend = 0, d = 0;
    if constexpr (MODE == 0) {
        row0 = bx * 128;
    } else {
        if (bx >= ts[ND_]) return;          // uniform per block
        while (bx >= ts[d + 1]) d++;
        row0 = offs[d] + (bx - ts[d]) * 128;
        vend = offs[d] + cnt[d];
    }
    const f16*   Bd    = Bt + (size_t)d * N * K;
    const float* biasd = (MODE == 0) ? bias : bias + d * N;
    const int    col0  = by * 128;

    // ---- staging setup: thread t owns chunks t and t+256 (rows t>>2, t>>2+64, colchunk t&3)
    const int rA0  = t >> 2;
    const int kcol = (t & 3) << 3;
    size_t arow0, arow1;
    if constexpr (MODE == 2) {
        arow0 = (size_t)rowmap[row0 + rA0];
        arow1 = (size_t)rowmap[row0 + rA0 + 64];
    } else {
        arow0 = (size_t)(row0 + rA0);
        arow1 = (size_t)(row0 + rA0 + 64);
    }
    const f16* aptr0 = A + arow0 * K + kcol;
    const f16* aptr1 = A + arow1 * K + kcol;
    const f16* bptr0 = Bd + (size_t)(col0 + rA0) * K + kcol;
    const f16* bptr1 = Bd + (size_t)(col0 + rA0 + 64) * K + kcol;
    f16* sA0 = sA + t * 8;  f16* sA1 = sA + (t + 256) * 8;
    f16* sB0 = sB + t * 8;  f16* sB1 = sB + (t + 256) * 8;

    // ---- wave/fragment geometry
    const int lane = t & 63, wid = t >> 6;
    const int l15 = lane & 15, kb = lane >> 4;
    const int wm = (wid >> 1) * 64, wn = (wid & 1) * 64;

    const f16* ra[4]; const f16* rb[4];
    #pragma unroll
    for (int i = 0; i < 4; i++) {
        ra[i] = sA + (((wm + i * 16 + l15) * 4 + kb) << 3);
        rb[i] = sB + (((wn + i * 16 + l15) * 4 + kb) << 3);
    }

    floatx4 acc[4][4] = {};

    for (int kt = 0; kt < K; kt += 32) {
        gload16(aptr0 + kt, sA0);
        gload16(aptr1 + kt, sA1);
        gload16(bptr0 + kt, sB0);
        gload16(bptr1 + kt, sB1);
        __syncthreads();                       // drains vmcnt -> tile ready
        half8 av[4], bv[4];
        #pragma unroll
        for (int i = 0; i < 4; i++) { av[i] = *(const half8*)ra[i]; bv[i] = *(const half8*)rb[i]; }
        #pragma unroll
        for (int i = 0; i < 4; i++)
            #pragma unroll
            for (int j = 0; j < 4; j++)
                acc[i][j] = __builtin_amdgcn_mfma_f32_16x16x32_f16(av[i], bv[j], acc[i][j], 0, 0, 0);
        __syncthreads();                       // protect LDS before next overwrite
    }

    // ---- epilogue: D row=(lane>>4)*4+e, col=lane&15
    #pragma unroll
    for (int j = 0; j < 4; j++) {
        const int n  = col0 + wn + j * 16 + l15;
        const float bb = biasd[n];
        #pragma unroll
        for (int i = 0; i < 4; i++) {
            #pragma unroll
            for (int e = 0; e < 4; e++) {
                const int m    = wm + i * 16 + kb * 4 + e;
                const int prow = row0 + m;
                float v = acc[i][j][e] + bb;
                if constexpr (MODE != 3) v = fmaxf(v, 0.0f);
                if constexpr (MODE == 0) {
                    outh[(size_t)prow * N + n] = (f16)v;
                } else if constexpr (MODE == 3) {
                    if (prow < vend) outf[(size_t)rowmap[prow] * SDIM_ + n] = v;
                } else {
                    if (prow < vend) outh[(size_t)prow * N + n] = (f16)v;
                }
            }
        }
    }
}

// ---------------- host ----------------
extern "C" void kernel_launch(void* const* d_in, const int* in_sizes, int n_in,
                              void* d_out, int out_size, void* d_ws, size_t ws_size,
                              hipStream_t stream)
{
    const float* z  = (const float*)d_in[0];
    const int*   y  = (const int*)d_in[1];
    const float* W0 = (const float*)d_in[2];
    const float* b0 = (const float*)d_in[3];
    const float* W1 = (const float*)d_in[4];
    const float* b1 = (const float*)d_in[5];
    const float* W2 = (const float*)d_in[6];
    const float* b2 = (const float*)d_in[7];
    const float* W3 = (const float*)d_in[8];
    const float* b3 = (const float*)d_in[9];
    const float* U1 = (const float*)d_in[10];
    const float* c1 = (const float*)d_in[11];
    const float* U2 = (const float*)d_in[12];
    const float* c2 = (const float*)d_in[13];
    const float* U3 = (const float*)d_in[14];
    const float* c3 = (const float*)d_in[15];
    const float* Uo = (const float*)d_in[16];
    const float* co = (const float*)d_in[17];
    float* out = (float*)d_out;

    char* p = (char*)d_ws;
    auto take = [&](size_t nbytes) { char* r = p; p += (nbytes + 255) & ~(size_t)255; return r; };
    int* cnt    = (int*)take(ND_ * 4);
    int* offs   = (int*)take((ND_ + 1) * 4);
    int* ts     = (int*)take((ND_ + 1) * 4);
    int* pos    = (int*)take((size_t)B_ * 4);
    int* rowmap = (int*)take((size_t)(B_ + 128) * 4);
    f16* zh  = (f16*)take((size_t)B_ * NZ_ * 2);
    f16* W0t = (f16*)take((size_t)H_ * NZ_ * 2);
    f16* W1t = (f16*)take((size_t)H_ * H_ * 2);
    f16* W2t = (f16*)take((size_t)H_ * H_ * 2);
    f16* W3t = (f16*)take((size_t)H_ * H_ * 2);
    f16* U1t = (f16*)take((size_t)ND_ * H_ * H_ * 2);
    f16* U2t = (f16*)take((size_t)ND_ * H_ * H_ * 2);
    f16* U3t = (f16*)take((size_t)ND_ * H_ * H_ * 2);
    f16* Uot = (f16*)take((size_t)ND_ * SDIM_ * H_ * 2);
    f16* hA  = (f16*)take((size_t)(B_ + 128) * H_ * 2);
    f16* hB  = (f16*)take((size_t)(B_ + 128) * H_ * 2);

    dim3 blk(256);

    prep_k<<<dim3(128, 10), blk, 0, stream>>>(W0, W1, W2, W3, U1, U2, U3, Uo, z,
                                              W0t, W1t, W2t, W3t, U1t, U2t, U3t, Uot, zh,
                                              cnt, rowmap);
    count_k  <<<dim3(B_ / 256), blk, 0, stream>>>(y, cnt, pos);
    prefix_k <<<dim3(1), dim3(64), 0, stream>>>(cnt, offs, ts);
    scatter_k<<<dim3(B_ / 256), blk, 0, stream>>>(y, pos, offs, rowmap);

    // trunk
    gemm_k<0><<<dim3(128, 4), blk, 0, stream>>>(zh, W0t, b0, hA, nullptr,
                                                nullptr, nullptr, nullptr, nullptr, 512, 64);
    gemm_k<0><<<dim3(128, 4), blk, 0, stream>>>(hA, W1t, b1, hB, nullptr,
                                                nullptr, nullptr, nullptr, nullptr, 512, 512);
    gemm_k<0><<<dim3(128, 4), blk, 0, stream>>>(hB, W2t, b2, hA, nullptr,
                                                nullptr, nullptr, nullptr, nullptr, 512, 512);
    gemm_k<0><<<dim3(128, 4), blk, 0, stream>>>(hA, W3t, b3, hB, nullptr,
                                                nullptr, nullptr, nullptr, nullptr, 512, 512);
    // branches on domain-sorted rows (136 = B/128 + ND worst-case tile slots)
    gemm_k<2><<<dim3(136, 4), blk, 0, stream>>>(hB, U1t, c1, hA, nullptr,
                                                offs, cnt, ts, rowmap, 512, 512);
    gemm_k<1><<<dim3(136, 4), blk, 0, stream>>>(hA, U2t, c2, hB, nullptr,
                                                offs, cnt, ts, rowmap, 512, 512);
    gemm_k<1><<<dim3(136, 4), blk, 0, stream>>>(hB, U3t, c3, hA, nullptr,
                                                offs, cnt, ts, rowmap, 512, 512);
    gemm_k<3><<<dim3(136, 1), blk, 0, stream>>>(hA, Uot, co, nullptr, out,
                                                offs, cnt, ts, rowmap, 128, 512);
}

// Round 2
// 176.842 us; speedup vs baseline: 1.5117x; 1.5117x over previous
//
#include <hip/hip_runtime.h>

#define B_    16384
#define NZ_   64
#define ND_   8
#define SDIM_ 128
#define H_    512

typedef _Float16 f16;
typedef __attribute__((ext_vector_type(4))) _Float16 half4;
typedef __attribute__((ext_vector_type(8))) _Float16 half8;
typedef __attribute__((ext_vector_type(4))) float floatx4;

// ---------------- async global->LDS, 16B per lane ----------------
__device__ __forceinline__ void gload16(const void* gp, void* lp) {
    void* g = const_cast<void*>(gp);
    __builtin_amdgcn_global_load_lds(
        (__attribute__((address_space(1))) void*)g,
        (__attribute__((address_space(3))) void*)lp, 16, 0, 0);
}

// ---------------- weight transpose: [*,K,N] f32 -> [*,N,K] f16, LDS-tiled ----------------
__device__ __forceinline__ void tr_mat(float (*t)[33], const float* __restrict__ s,
                                       f16* __restrict__ d, int K, int N, int tl) {
    const int ntk = K >> 5;
    const int per = ntk * (N >> 5);
    const int bt  = tl / per;
    const int w   = tl - bt * per;
    s += (size_t)bt * K * N;
    d += (size_t)bt * K * N;
    const int k0 = (w % ntk) << 5, n0 = (w / ntk) << 5;
    const int tid = threadIdx.x;
    {
        const int nn = tid & 31, k4 = tid >> 5;
        #pragma unroll
        for (int p = 0; p < 4; p++)
            t[k4 + p * 8][nn] = s[(size_t)(k0 + k4 + p * 8) * N + n0 + nn];
    }
    __syncthreads();
    {
        const int kk = tid & 31, n4 = tid >> 5;
        #pragma unroll
        for (int p = 0; p < 4; p++)
            d[(size_t)(n0 + n4 + p * 8) * K + k0 + kk] = (f16)t[kk][n4 + p * 8];
    }
}

__global__ __launch_bounds__(256) void tr_k(
    const float* W0, const float* W1, const float* W2, const float* W3,
    const float* U1, const float* U2, const float* U3, const float* Uo,
    f16* W0t, f16* W1t, f16* W2t, f16* W3t,
    f16* U1t, f16* U2t, f16* U3t, f16* Uot)
{
    __shared__ float t[32][33];
    int tl = blockIdx.x;
    if (tl < 32)   { tr_mat(t, W0, W0t, 64, 512, tl); return; }  tl -= 32;
    if (tl < 256)  { tr_mat(t, W1, W1t, 512, 512, tl); return; } tl -= 256;
    if (tl < 256)  { tr_mat(t, W2, W2t, 512, 512, tl); return; } tl -= 256;
    if (tl < 256)  { tr_mat(t, W3, W3t, 512, 512, tl); return; } tl -= 256;
    if (tl < 2048) { tr_mat(t, U1, U1t, 512, 512, tl); return; } tl -= 2048;
    if (tl < 2048) { tr_mat(t, U2, U2t, 512, 512, tl); return; } tl -= 2048;
    if (tl < 2048) { tr_mat(t, U3, U3t, 512, 512, tl); return; } tl -= 2048;
    tr_mat(t, Uo, Uot, 512, 128, tl);
}
#define TR_BLOCKS 7456

// ---------------- misc: z f32->f16 (vectorized) + zero counters/pad ----------------
__global__ __launch_bounds__(256) void misc_k(const float* __restrict__ z,
                                              f16* __restrict__ zh,
                                              int* __restrict__ cnt,
                                              int* __restrict__ rowmap) {
    const int i = blockIdx.x * 256 + threadIdx.x;   // grid 1024 -> covers B*NZ/4
    float4 v = ((const float4*)z)[i];
    half4 h = { (f16)v.x, (f16)v.y, (f16)v.z, (f16)v.w };
    ((half4*)zh)[i] = h;
    if (blockIdx.x == 0 && threadIdx.x < ND_) cnt[threadIdx.x] = 0;
    if (blockIdx.x == 1 && threadIdx.x < 128) rowmap[B_ + threadIdx.x] = 0;
}

// ---------------- domain sort: LDS-histogram count -> prefix -> ranked scatter ----------------
__global__ __launch_bounds__(256) void count_k(const int* __restrict__ y,
                                               int* __restrict__ cnt) {
    __shared__ int h[ND_];
    if (threadIdx.x < ND_) h[threadIdx.x] = 0;
    __syncthreads();
    atomicAdd(&h[y[blockIdx.x * 256 + threadIdx.x]], 1);   // grid exactly covers B_
    __syncthreads();
    if (threadIdx.x < ND_) atomicAdd(&cnt[threadIdx.x], h[threadIdx.x]);
}

__global__ void prefix_k(const int* __restrict__ cnt, int* __restrict__ offs,
                         int* __restrict__ ts, int* __restrict__ running) {
    if (threadIdx.x == 0) {
        int o = 0, tt = 0;
        offs[0] = 0; ts[0] = 0;
        for (int d = 0; d < ND_; d++) {
            running[d] = o;
            o += cnt[d];               offs[d + 1] = o;
            tt += (cnt[d] + 127) >> 7; ts[d + 1] = tt;
        }
    }
}

__global__ __launch_bounds__(256) void scatter_k(const int* __restrict__ y,
                                                 int* __restrict__ running,
                                                 int* __restrict__ rowmap) {
    __shared__ int h[ND_], base[ND_];
    if (threadIdx.x < ND_) h[threadIdx.x] = 0;
    __syncthreads();
    const int b = blockIdx.x * 256 + threadIdx.x;   // grid exactly covers B_
    const int d = y[b];
    const int r = atomicAdd(&h[d], 1);
    __syncthreads();
    if (threadIdx.x < ND_) base[threadIdx.x] = atomicAdd(&running[threadIdx.x], h[threadIdx.x]);
    __syncthreads();
    rowmap[base[d] + r] = b;
}

// ---------------- fused GEMM: C = act(A @ W + bias) ----------------
// A: [rows][K] f16 row-major.  Bt: weights TRANSPOSED [*, N][K] f16.
// 128x128 tile, 4 waves (2x2), BK=32, m97 structure.
// MODE 0: trunk  — dense rows, f16 out, relu
// MODE 1: branch — domain-tiled, f16 out (permuted buffer), relu, masked store
// MODE 2: branch+gather — as 1 but A rows via rowmap
// MODE 3: final  — domain-tiled, f32 scatter to d_out via rowmap, +bias, no relu
template<int MODE>
__global__ __launch_bounds__(256, 2) void gemm_k(
    const f16* __restrict__ A, const f16* __restrict__ Bt,
    const float* __restrict__ bias,
    f16* __restrict__ outh, float* __restrict__ outf,
    const int* __restrict__ offs, const int* __restrict__ cnt,
    const int* __restrict__ ts, const int* __restrict__ rowmap,
    int N, int K)
{
    __shared__ f16 sA[128 * 32];   // 8 KB, [row][k] chunks of 8 f16
    __shared__ f16 sB[128 * 32];   // 8 KB, [n][k]

    const int t  = threadIdx.x;
    const int bx = blockIdx.x, by = blockIdx.y;

    int row0, vend = 0, d = 0;
    if constexpr (MODE == 0) {
        row0 = bx * 128;
    } else {
        if (bx >= ts[ND_]) return;          // uniform per block
        while (bx >= ts[d + 1]) d++;
        row0 = offs[d] + (bx - ts[d]) * 128;
        vend = offs[d] + cnt[d];
    }
    const f16*   Bd    = Bt + (size_t)d * N * K;
    const float* biasd = (MODE == 0) ? bias : bias + d * N;
    const int    col0  = by * 128;

    // ---- staging: thread t owns chunks t and t+256 (rows t>>2, t>>2+64, colchunk t&3)
    const int rA0  = t >> 2;
    const int kcol = (t & 3) << 3;
    size_t arow0, arow1;
    if constexpr (MODE == 2) {
        arow0 = (size_t)rowmap[row0 + rA0];
        arow1 = (size_t)rowmap[row0 + rA0 + 64];
    } else {
        arow0 = (size_t)(row0 + rA0);
        arow1 = (size_t)(row0 + rA0 + 64);
    }
    const f16* aptr0 = A + arow0 * K + kcol;
    const f16* aptr1 = A + arow1 * K + kcol;
    const f16* bptr0 = Bd + (size_t)(col0 + rA0) * K + kcol;
    const f16* bptr1 = Bd + (size_t)(col0 + rA0 + 64) * K + kcol;
    f16* sA0 = sA + t * 8;  f16* sA1 = sA + (t + 256) * 8;
    f16* sB0 = sB + t * 8;  f16* sB1 = sB + (t + 256) * 8;

    // ---- wave/fragment geometry
    const int lane = t & 63, wid = t >> 6;
    const int l15 = lane & 15, kb = lane >> 4;
    const int wm = (wid >> 1) * 64, wn = (wid & 1) * 64;

    const f16* ra[4]; const f16* rb[4];
    #pragma unroll
    for (int i = 0; i < 4; i++) {
        ra[i] = sA + (((wm + i * 16 + l15) * 4 + kb) << 3);
        rb[i] = sB + (((wn + i * 16 + l15) * 4 + kb) << 3);
    }

    floatx4 acc[4][4] = {};

    for (int kt = 0; kt < K; kt += 32) {
        gload16(aptr0 + kt, sA0);
        gload16(aptr1 + kt, sA1);
        gload16(bptr0 + kt, sB0);
        gload16(bptr1 + kt, sB1);
        __syncthreads();                       // drains vmcnt -> tile ready
        half8 av[4], bv[4];
        #pragma unroll
        for (int i = 0; i < 4; i++) { av[i] = *(const half8*)ra[i]; bv[i] = *(const half8*)rb[i]; }
        #pragma unroll
        for (int i = 0; i < 4; i++)
            #pragma unroll
            for (int j = 0; j < 4; j++)
                acc[i][j] = __builtin_amdgcn_mfma_f32_16x16x32_f16(av[i], bv[j], acc[i][j], 0, 0, 0);
        __syncthreads();                       // protect LDS before next overwrite
    }

    // ---- epilogue: D row=(lane>>4)*4+e, col=lane&15
    #pragma unroll
    for (int j = 0; j < 4; j++) {
        const int n  = col0 + wn + j * 16 + l15;
        const float bb = biasd[n];
        #pragma unroll
        for (int i = 0; i < 4; i++) {
            #pragma unroll
            for (int e = 0; e < 4; e++) {
                const int m    = wm + i * 16 + kb * 4 + e;
                const int prow = row0 + m;
                float v = acc[i][j][e] + bb;
                if constexpr (MODE != 3) v = fmaxf(v, 0.0f);
                if constexpr (MODE == 0) {
                    outh[(size_t)prow * N + n] = (f16)v;
                } else if constexpr (MODE == 3) {
                    if (prow < vend) outf[(size_t)rowmap[prow] * SDIM_ + n] = v;
                } else {
                    if (prow < vend) outh[(size_t)prow * N + n] = (f16)v;
                }
            }
        }
    }
}

// ---------------- host ----------------
extern "C" void kernel_launch(void* const* d_in, const int* in_sizes, int n_in,
                              void* d_out, int out_size, void* d_ws, size_t ws_size,
                              hipStream_t stream)
{
    const float* z  = (const float*)d_in[0];
    const int*   y  = (const int*)d_in[1];
    const float* W0 = (const float*)d_in[2];
    const float* b0 = (const float*)d_in[3];
    const float* W1 = (const float*)d_in[4];
    const float* b1 = (const float*)d_in[5];
    const float* W2 = (const float*)d_in[6];
    const float* b2 = (const float*)d_in[7];
    const float* W3 = (const float*)d_in[8];
    const float* b3 = (const float*)d_in[9];
    const float* U1 = (const float*)d_in[10];
    const float* c1 = (const float*)d_in[11];
    const float* U2 = (const float*)d_in[12];
    const float* c2 = (const float*)d_in[13];
    const float* U3 = (const float*)d_in[14];
    const float* c3 = (const float*)d_in[15];
    const float* Uo = (const float*)d_in[16];
    const float* co = (const float*)d_in[17];
    float* out = (float*)d_out;

    char* p = (char*)d_ws;
    auto take = [&](size_t nbytes) { char* r = p; p += (nbytes + 255) & ~(size_t)255; return r; };
    int* cnt     = (int*)take(ND_ * 4);
    int* offs    = (int*)take((ND_ + 1) * 4);
    int* ts      = (int*)take((ND_ + 1) * 4);
    int* running = (int*)take(ND_ * 4);
    int* rowmap  = (int*)take((size_t)(B_ + 128) * 4);
    f16* zh  = (f16*)take((size_t)B_ * NZ_ * 2);
    f16* W0t = (f16*)take((size_t)H_ * NZ_ * 2);
    f16* W1t = (f16*)take((size_t)H_ * H_ * 2);
    f16* W2t = (f16*)take((size_t)H_ * H_ * 2);
    f16* W3t = (f16*)take((size_t)H_ * H_ * 2);
    f16* U1t = (f16*)take((size_t)ND_ * H_ * H_ * 2);
    f16* U2t = (f16*)take((size_t)ND_ * H_ * H_ * 2);
    f16* U3t = (f16*)take((size_t)ND_ * H_ * H_ * 2);
    f16* Uot = (f16*)take((size_t)ND_ * SDIM_ * H_ * 2);
    f16* hA  = (f16*)take((size_t)(B_ + 128) * H_ * 2);
    f16* hB  = (f16*)take((size_t)(B_ + 128) * H_ * 2);

    dim3 blk(256);

    tr_k<<<dim3(TR_BLOCKS), blk, 0, stream>>>(W0, W1, W2, W3, U1, U2, U3, Uo,
                                              W0t, W1t, W2t, W3t, U1t, U2t, U3t, Uot);
    misc_k   <<<dim3(1024), blk, 0, stream>>>(z, zh, cnt, rowmap);
    count_k  <<<dim3(B_ / 256), blk, 0, stream>>>(y, cnt);
    prefix_k <<<dim3(1), dim3(64), 0, stream>>>(cnt, offs, ts, running);
    scatter_k<<<dim3(B_ / 256), blk, 0, stream>>>(y, running, rowmap);

    // trunk
    gemm_k<0><<<dim3(128, 4), blk, 0, stream>>>(zh, W0t, b0, hA, nullptr,
                                                nullptr, nullptr, nullptr, nullptr, 512, 64);
    gemm_k<0><<<dim3(128, 4), blk, 0, stream>>>(hA, W1t, b1, hB, nullptr,
                                                nullptr, nullptr, nullptr, nullptr, 512, 512);
    gemm_k<0><<<dim3(128, 4), blk, 0, stream>>>(hB, W2t, b2, hA, nullptr,
                                                nullptr, nullptr, nullptr, nullptr, 512, 512);
    gemm_k<0><<<dim3(128, 4), blk, 0, stream>>>(hA, W3t, b3, hB, nullptr,
                                                nullptr, nullptr, nullptr, nullptr, 512, 512);
    // branches on domain-sorted rows (136 = B/128 + ND worst-case tile slots)
    gemm_k<2><<<dim3(136, 4), blk, 0, stream>>>(hB, U1t, c1, hA, nullptr,
                                                offs, cnt, ts, rowmap, 512, 512);
    gemm_k<1><<<dim3(136, 4), blk, 0, stream>>>(hA, U2t, c2, hB, nullptr,
                                                offs, cnt, ts, rowmap, 512, 512);
    gemm_k<1><<<dim3(136, 4), blk, 0, stream>>>(hB, U3t, c3, hA, nullptr,
                                                offs, cnt, ts, rowmap, 512, 512);
    gemm_k<3><<<dim3(136, 1), blk, 0, stream>>>(hA, Uot, co, nullptr, out,
                                                offs, cnt, ts, rowmap, 128, 512);
}

// Round 3
// 108.823 us; speedup vs baseline: 2.4566x; 1.6250x over previous
//
#include <hip/hip_runtime.h>

#define B_    16384
#define NZ_   64
#define ND_   8
#define SDIM_ 128
#define H_    512

typedef _Float16 f16;
typedef __attribute__((ext_vector_type(4))) _Float16 half4;
typedef __attribute__((ext_vector_type(8))) _Float16 half8;
typedef __attribute__((ext_vector_type(4))) float floatx4;

// swizzled LDS byte offset for panel element (row, byte-col); panel stride 1024B.
// XOR bits 4-6 with row&7 -> 16 lanes reading a column hit 8 distinct 16B granules.
__device__ __forceinline__ int pswz(int row, int colbyte) {
    return (row * 1024 + colbyte) ^ ((row & 7) << 4);
}

// ---------------- weight pack: [*,K,N] f32 -> fragment-tiled f16 ----------------
// packed element ((nt*(K/32) + kt)*64 + lane)*8 + j  ==  W[kt*32 + (lane>>4)*8 + j][nt*16 + (lane&15)]
// so a wave's B-fragment load is one coalesced 1KB global_load_dwordx4.
__device__ __forceinline__ void tr_mat(float (*tb)[33], const float* __restrict__ s,
                                       f16* __restrict__ dd, int K, int N, int tl) {
    const int ntk = K >> 5;
    const int per = ntk * (N >> 5);
    const int bt  = tl / per;
    const int w   = tl - bt * per;
    s  += (size_t)bt * K * N;
    dd += (size_t)bt * K * N;
    const int k0 = (w % ntk) << 5, n0 = (w / ntk) << 5;
    const int tid = threadIdx.x;
    {
        const int nn = tid & 31, k4 = tid >> 5;
        #pragma unroll
        for (int p = 0; p < 4; p++)
            tb[k4 + p * 8][nn] = s[(size_t)(k0 + k4 + p * 8) * N + n0 + nn];
    }
    __syncthreads();
    {
        const int sub = tid >> 7, r = tid & 127;
        const int lane = r >> 1, jp = (r & 1) * 4;
        const int kb = lane >> 4, l15 = lane & 15;
        const size_t base = ((size_t)((n0 >> 4) + sub) * (K >> 5) + (k0 >> 5)) * 512
                          + lane * 8 + jp;
        half4 h;
        #pragma unroll
        for (int jj = 0; jj < 4; jj++)
            h[jj] = (f16)tb[kb * 8 + jp + jj][sub * 16 + l15];
        *(half4*)(dd + base) = h;
    }
}

__global__ __launch_bounds__(256) void tr_k(
    const float* W0, const float* W1, const float* W2, const float* W3,
    const float* U1, const float* U2, const float* U3, const float* Uo,
    f16* W0t, f16* W1t, f16* W2t, f16* W3t,
    f16* U1t, f16* U2t, f16* U3t, f16* Uot)
{
    __shared__ float tb[32][33];
    int tl = blockIdx.x;
    if (tl < 32)   { tr_mat(tb, W0, W0t, 64, 512, tl); return; }  tl -= 32;
    if (tl < 256)  { tr_mat(tb, W1, W1t, 512, 512, tl); return; } tl -= 256;
    if (tl < 256)  { tr_mat(tb, W2, W2t, 512, 512, tl); return; } tl -= 256;
    if (tl < 256)  { tr_mat(tb, W3, W3t, 512, 512, tl); return; } tl -= 256;
    if (tl < 2048) { tr_mat(tb, U1, U1t, 512, 512, tl); return; } tl -= 2048;
    if (tl < 2048) { tr_mat(tb, U2, U2t, 512, 512, tl); return; } tl -= 2048;
    if (tl < 2048) { tr_mat(tb, U3, U3t, 512, 512, tl); return; } tl -= 2048;
    tr_mat(tb, Uo, Uot, 512, 128, tl);
}
#define TR_BLOCKS 7456

// ---------------- domain sort ----------------
__global__ void misc_k(int* __restrict__ cnt, int* __restrict__ rowmap) {
    const int t = threadIdx.x;
    if (t < ND_) cnt[t] = 0;
    if (t < 128) rowmap[B_ + t] = 0;     // pad for last-domain tail tile
}

__global__ __launch_bounds__(256) void count_k(const int* __restrict__ y,
                                               int* __restrict__ cnt) {
    __shared__ int h[ND_];
    if (threadIdx.x < ND_) h[threadIdx.x] = 0;
    __syncthreads();
    atomicAdd(&h[y[blockIdx.x * 256 + threadIdx.x]], 1);   // grid covers B_ exactly
    __syncthreads();
    if (threadIdx.x < ND_) atomicAdd(&cnt[threadIdx.x], h[threadIdx.x]);
}

__global__ void prefix_k(const int* __restrict__ cnt, int* __restrict__ offs,
                         int* __restrict__ running) {
    if (threadIdx.x == 0) {
        int o = 0;
        offs[0] = 0;
        for (int d = 0; d < ND_; d++) { running[d] = o; o += cnt[d]; offs[d + 1] = o; }
    }
}

__global__ __launch_bounds__(256) void scatter_k(const int* __restrict__ y,
                                                 int* __restrict__ running,
                                                 int* __restrict__ rowmap) {
    __shared__ int h[ND_], base[ND_];
    if (threadIdx.x < ND_) h[threadIdx.x] = 0;
    __syncthreads();
    const int b = blockIdx.x * 256 + threadIdx.x;
    const int d = y[b];
    const int r = atomicAdd(&h[d], 1);
    __syncthreads();
    if (threadIdx.x < ND_) base[threadIdx.x] = atomicAdd(&running[threadIdx.x], h[threadIdx.x]);
    __syncthreads();
    rowmap[base[d] + r] = b;
}

// ---------------- one fused layer: panel(LDS) @ Wpacked -> panel / out ----------------
// 8 waves, wave w owns all rows x cols [w*NFRAG*16, ...). B-frags stream from
// global (fragment-packed, coalesced), reg double-buffered one k-step ahead.
template<int MFRAG, int NFRAG, int KT, bool RELU, bool TOPANEL>
__device__ __forceinline__ void layer_f(
    char* lds, const f16* __restrict__ Wp, const float* __restrict__ bias,
    float* __restrict__ outf, const int* __restrict__ rowmap,
    int row0, int vend)
{
    const int t = threadIdx.x;
    const int lane = t & 63, wid = t >> 6;
    const int l15 = lane & 15, kb = lane >> 4;
    const int swz = (l15 & 7) << 4;

    int baseA[MFRAG];
    #pragma unroll
    for (int m = 0; m < MFRAG; m++)
        baseA[m] = (((m * 16 + l15) * 1024) + kb * 16) ^ swz;   // k-step advances via ^ (kt<<6)

    const half8* wp = (const half8*)Wp;
    int idxB[NFRAG];
    #pragma unroll
    for (int n = 0; n < NFRAG; n++)
        idxB[n] = ((wid * NFRAG + n) * KT) * 64 + lane;

    floatx4 acc[MFRAG][NFRAG] = {};
    half8 a[2][MFRAG], b[2][NFRAG];

    #pragma unroll
    for (int m = 0; m < MFRAG; m++) a[0][m] = *(const half8*)(lds + baseA[m]);
    #pragma unroll
    for (int n = 0; n < NFRAG; n++) b[0][n] = wp[idxB[n]];

    #pragma unroll
    for (int kt = 0; kt < KT; kt++) {
        const int cur = kt & 1, nxt = cur ^ 1;
        if (kt + 1 < KT) {
            #pragma unroll
            for (int m = 0; m < MFRAG; m++)
                a[nxt][m] = *(const half8*)(lds + (baseA[m] ^ ((kt + 1) << 6)));
            #pragma unroll
            for (int n = 0; n < NFRAG; n++)
                b[nxt][n] = wp[idxB[n] + (kt + 1) * 64];
        }
        #pragma unroll
        for (int m = 0; m < MFRAG; m++)
            #pragma unroll
            for (int n = 0; n < NFRAG; n++)
                acc[m][n] = __builtin_amdgcn_mfma_f32_16x16x32_f16(a[cur][m], b[cur][n], acc[m][n], 0, 0, 0);
    }

    __syncthreads();   // all waves done reading panel

    #pragma unroll
    for (int n = 0; n < NFRAG; n++) {
        const int col = wid * (NFRAG * 16) + n * 16 + l15;
        const float bb = bias[col];
        #pragma unroll
        for (int m = 0; m < MFRAG; m++) {
            #pragma unroll
            for (int e = 0; e < 4; e++) {
                const int row = m * 16 + kb * 4 + e;
                float v = acc[m][n][e] + bb;
                if constexpr (RELU) v = fmaxf(v, 0.0f);
                if constexpr (TOPANEL) {
                    *(f16*)(lds + pswz(row, col * 2)) = (f16)v;
                } else {
                    const int pr = row0 + row;
                    if (pr < vend) outf[(size_t)rowmap[pr] * SDIM_ + col] = v;
                }
            }
        }
    }
    if constexpr (TOPANEL) __syncthreads();   // panel is next layer's input
}

// ---------------- fused trunk: z -> 4 layers -> hT ----------------
__global__ __launch_bounds__(512, 2) void trunk_k(
    const float* __restrict__ z,
    const f16* __restrict__ W0p, const float* __restrict__ b0,
    const f16* __restrict__ W1p, const float* __restrict__ b1,
    const f16* __restrict__ W2p, const float* __restrict__ b2,
    const f16* __restrict__ W3p, const float* __restrict__ b3,
    f16* __restrict__ hT)
{
    extern __shared__ char lds[];
    const int t = threadIdx.x;
    const int row0 = blockIdx.x * 64;

    {   // fill panel with z rows (f32 -> f16), swizzled
        const int r = t >> 3, c = (t & 7) * 8;
        const float4 v0 = *(const float4*)(z + (size_t)(row0 + r) * NZ_ + c);
        const float4 v1 = *(const float4*)(z + (size_t)(row0 + r) * NZ_ + c + 4);
        half8 h = { (f16)v0.x, (f16)v0.y, (f16)v0.z, (f16)v0.w,
                    (f16)v1.x, (f16)v1.y, (f16)v1.z, (f16)v1.w };
        *(half8*)(lds + pswz(r, c * 2)) = h;
    }
    __syncthreads();

    layer_f<4, 4, 2,  true, true>(lds, W0p, b0, nullptr, nullptr, 0, 0);
    layer_f<4, 4, 16, true, true>(lds, W1p, b1, nullptr, nullptr, 0, 0);
    layer_f<4, 4, 16, true, true>(lds, W2p, b2, nullptr, nullptr, 0, 0);
    layer_f<4, 4, 16, true, true>(lds, W3p, b3, nullptr, nullptr, 0, 0);

    {   // coalesced panel -> hT
        const int r = t >> 3;
        #pragma unroll
        for (int p = 0; p < 8; p++) {
            const int c16 = (t & 7) + p * 8;
            half8 h = *(const half8*)(lds + pswz(r, c16 * 16));
            *(half8*)(hT + (size_t)(row0 + r) * H_ + c16 * 8) = h;
        }
    }
}

// ---------------- fused branches: gather -> 3 layers -> out scatter ----------------
// tile i of domain d = block (d + 8*i): XCD-pinned so each XCD streams one
// domain's weights (1.7 MB, per-XCD-L2 resident).
__global__ __launch_bounds__(512, 2) void branch_k(
    const f16* __restrict__ hT,
    const f16* __restrict__ U1p, const float* __restrict__ c1,
    const f16* __restrict__ U2p, const float* __restrict__ c2,
    const f16* __restrict__ U3p, const float* __restrict__ c3,
    const f16* __restrict__ Uop, const float* __restrict__ co,
    const int* __restrict__ offs, const int* __restrict__ cnt,
    const int* __restrict__ rowmap, float* __restrict__ out)
{
    extern __shared__ char lds[];
    const int d = blockIdx.x & 7, i = blockIdx.x >> 3;
    const int c = cnt[d];
    if (i * 80 >= c) return;
    const int row0 = offs[d] + i * 80;
    const int vend = offs[d] + c;
    const int t = threadIdx.x;

    // gather 80 trunk rows into swizzled panel (per-row fully coalesced)
    #pragma unroll
    for (int p = 0; p < 10; p++) {
        const int r   = p * 8 + (t >> 6);
        const int c16 = t & 63;
        const int src = rowmap[row0 + r];
        half8 h = *(const half8*)(hT + (size_t)src * H_ + c16 * 8);
        *(half8*)(lds + pswz(r, c16 * 16)) = h;
    }
    __syncthreads();

    layer_f<5, 4, 16, true,  true >(lds, U1p + (size_t)d * H_ * H_,    c1 + d * H_,    nullptr, nullptr, 0, 0);
    layer_f<5, 4, 16, true,  true >(lds, U2p + (size_t)d * H_ * H_,    c2 + d * H_,    nullptr, nullptr, 0, 0);
    layer_f<5, 4, 16, true,  true >(lds, U3p + (size_t)d * H_ * H_,    c3 + d * H_,    nullptr, nullptr, 0, 0);
    layer_f<5, 1, 16, false, false>(lds, Uop + (size_t)d * H_ * SDIM_, co + d * SDIM_, out, rowmap, row0, vend);
}

// ---------------- host ----------------
extern "C" void kernel_launch(void* const* d_in, const int* in_sizes, int n_in,
                              void* d_out, int out_size, void* d_ws, size_t ws_size,
                              hipStream_t stream)
{
    const float* z  = (const float*)d_in[0];
    const int*   y  = (const int*)d_in[1];
    const float* W0 = (const float*)d_in[2];
    const float* b0 = (const float*)d_in[3];
    const float* W1 = (const float*)d_in[4];
    const float* b1 = (const float*)d_in[5];
    const float* W2 = (const float*)d_in[6];
    const float* b2 = (const float*)d_in[7];
    const float* W3 = (const float*)d_in[8];
    const float* b3 = (const float*)d_in[9];
    const float* U1 = (const float*)d_in[10];
    const float* c1 = (const float*)d_in[11];
    const float* U2 = (const float*)d_in[12];
    const float* c2 = (const float*)d_in[13];
    const float* U3 = (const float*)d_in[14];
    const float* c3 = (const float*)d_in[15];
    const float* Uo = (const float*)d_in[16];
    const float* co = (const float*)d_in[17];
    float* out = (float*)d_out;

    char* p = (char*)d_ws;
    auto take = [&](size_t nbytes) { char* r = p; p += (nbytes + 255) & ~(size_t)255; return r; };
    int* cnt     = (int*)take(ND_ * 4);
    int* offs    = (int*)take((ND_ + 1) * 4);
    int* running = (int*)take(ND_ * 4);
    int* rowmap  = (int*)take((size_t)(B_ + 128) * 4);
    f16* W0t = (f16*)take((size_t)H_ * NZ_ * 2);
    f16* W1t = (f16*)take((size_t)H_ * H_ * 2);
    f16* W2t = (f16*)take((size_t)H_ * H_ * 2);
    f16* W3t = (f16*)take((size_t)H_ * H_ * 2);
    f16* U1t = (f16*)take((size_t)ND_ * H_ * H_ * 2);
    f16* U2t = (f16*)take((size_t)ND_ * H_ * H_ * 2);
    f16* U3t = (f16*)take((size_t)ND_ * H_ * H_ * 2);
    f16* Uot = (f16*)take((size_t)ND_ * SDIM_ * H_ * 2);
    f16* hT  = (f16*)take((size_t)B_ * H_ * 2);

    hipFuncSetAttribute((const void*)trunk_k,  hipFuncAttributeMaxDynamicSharedMemorySize, 64 * 1024);
    hipFuncSetAttribute((const void*)branch_k, hipFuncAttributeMaxDynamicSharedMemorySize, 80 * 1024);

    misc_k   <<<dim3(1), dim3(256), 0, stream>>>(cnt, rowmap);
    count_k  <<<dim3(B_ / 256), dim3(256), 0, stream>>>(y, cnt);
    prefix_k <<<dim3(1), dim3(64), 0, stream>>>(cnt, offs, running);
    scatter_k<<<dim3(B_ / 256), dim3(256), 0, stream>>>(y, running, rowmap);

    tr_k<<<dim3(TR_BLOCKS), dim3(256), 0, stream>>>(W0, W1, W2, W3, U1, U2, U3, Uo,
                                                    W0t, W1t, W2t, W3t, U1t, U2t, U3t, Uot);

    trunk_k<<<dim3(B_ / 64), dim3(512), 64 * 1024, stream>>>(
        z, W0t, b0, W1t, b1, W2t, b2, W3t, b3, hT);

    branch_k<<<dim3(8 * (B_ / 80 + 1)), dim3(512), 80 * 1024, stream>>>(
        hT, U1t, c1, U2t, c2, U3t, c3, Uot, co, offs, cnt, rowmap, out);
}

// Round 4
// 102.074 us; speedup vs baseline: 2.6190x; 1.0661x over previous
//
#include <hip/hip_runtime.h>

#define B_    16384
#define NZ_   64
#define ND_   8
#define SDIM_ 128
#define H_    512

typedef _Float16 f16;
typedef __attribute__((ext_vector_type(4))) _Float16 half4;
typedef __attribute__((ext_vector_type(8))) _Float16 half8;
typedef __attribute__((ext_vector_type(4))) float floatx4;

// swizzle byte-bits 4-6 with (row>>1)&7.  Conflict-free for BOTH the b128
// A-frag reads (granule = kb ^ (l15>>1): 8 lanes/granule, uniform) and the
// scalar f16 epilogue writes (rows kb*4+e -> (kb*2+(e>>1))&7: 4 distinct
// granules over kb; the old (row&7) swizzle collided kb=0,2 and kb=1,3 -> 4-way).
__device__ __forceinline__ int pswz(int row, int colbyte) {
    return (row * 1024 + colbyte) ^ (((row >> 1) & 7) << 4);
}

// ---------------- weight pack: [*,K,N] f32 -> fragment-tiled f16 ----------------
// packed ((nt*(K/32) + kt)*64 + lane)*8 + j == W[kt*32 + (lane>>4)*8 + j][nt*16 + (lane&15)]
__device__ __forceinline__ void tr_mat(float (*tb)[33], const float* __restrict__ s,
                                       f16* __restrict__ dd, int K, int N, int tl) {
    const int ntk = K >> 5;
    const int per = ntk * (N >> 5);
    const int bt  = tl / per;
    const int w   = tl - bt * per;
    s  += (size_t)bt * K * N;
    dd += (size_t)bt * K * N;
    const int k0 = (w % ntk) << 5, n0 = (w / ntk) << 5;
    const int tid = threadIdx.x;
    {
        const int nn = tid & 31, k4 = tid >> 5;
        #pragma unroll
        for (int p = 0; p < 4; p++)
            tb[k4 + p * 8][nn] = s[(size_t)(k0 + k4 + p * 8) * N + n0 + nn];
    }
    __syncthreads();
    {
        const int sub = tid >> 7, r = tid & 127;
        const int lane = r >> 1, jp = (r & 1) * 4;
        const int kb = lane >> 4, l15 = lane & 15;
        const size_t base = ((size_t)((n0 >> 4) + sub) * (K >> 5) + (k0 >> 5)) * 512
                          + lane * 8 + jp;
        half4 h;
        #pragma unroll
        for (int jj = 0; jj < 4; jj++)
            h[jj] = (f16)tb[kb * 8 + jp + jj][sub * 16 + l15];
        *(half4*)(dd + base) = h;
    }
}

__global__ __launch_bounds__(256) void tr_k(
    const float* W0, const float* W1, const float* W2, const float* W3,
    const float* U1, const float* U2, const float* U3, const float* Uo,
    f16* W0t, f16* W1t, f16* W2t, f16* W3t,
    f16* U1t, f16* U2t, f16* U3t, f16* Uot)
{
    __shared__ float tb[32][33];
    int tl = blockIdx.x;
    if (tl < 32)   { tr_mat(tb, W0, W0t, 64, 512, tl); return; }  tl -= 32;
    if (tl < 256)  { tr_mat(tb, W1, W1t, 512, 512, tl); return; } tl -= 256;
    if (tl < 256)  { tr_mat(tb, W2, W2t, 512, 512, tl); return; } tl -= 256;
    if (tl < 256)  { tr_mat(tb, W3, W3t, 512, 512, tl); return; } tl -= 256;
    if (tl < 2048) { tr_mat(tb, U1, U1t, 512, 512, tl); return; } tl -= 2048;
    if (tl < 2048) { tr_mat(tb, U2, U2t, 512, 512, tl); return; } tl -= 2048;
    if (tl < 2048) { tr_mat(tb, U3, U3t, 512, 512, tl); return; } tl -= 2048;
    tr_mat(tb, Uo, Uot, 512, 128, tl);
}
#define TR_BLOCKS 7456

// ---------------- domain sort ----------------
__global__ void misc_k(int* __restrict__ cnt, int* __restrict__ rowmap) {
    const int t = threadIdx.x;
    if (t < ND_) cnt[t] = 0;
    if (t < 128) rowmap[B_ + t] = 0;     // pad for last-domain tail tile
}

__global__ __launch_bounds__(256) void count_k(const int* __restrict__ y,
                                               int* __restrict__ cnt) {
    __shared__ int h[ND_];
    if (threadIdx.x < ND_) h[threadIdx.x] = 0;
    __syncthreads();
    atomicAdd(&h[y[blockIdx.x * 256 + threadIdx.x]], 1);   // grid covers B_ exactly
    __syncthreads();
    if (threadIdx.x < ND_) atomicAdd(&cnt[threadIdx.x], h[threadIdx.x]);
}

__global__ void prefix_k(const int* __restrict__ cnt, int* __restrict__ offs,
                         int* __restrict__ running) {
    if (threadIdx.x == 0) {
        int o = 0;
        offs[0] = 0;
        for (int d = 0; d < ND_; d++) { running[d] = o; o += cnt[d]; offs[d + 1] = o; }
    }
}

__global__ __launch_bounds__(256) void scatter_k(const int* __restrict__ y,
                                                 int* __restrict__ running,
                                                 int* __restrict__ rowmap) {
    __shared__ int h[ND_], base[ND_];
    if (threadIdx.x < ND_) h[threadIdx.x] = 0;
    __syncthreads();
    const int b = blockIdx.x * 256 + threadIdx.x;
    const int d = y[b];
    const int r = atomicAdd(&h[d], 1);
    __syncthreads();
    if (threadIdx.x < ND_) base[threadIdx.x] = atomicAdd(&running[threadIdx.x], h[threadIdx.x]);
    __syncthreads();
    rowmap[base[d] + r] = b;
}

// ---------------- one fused layer with rolling cross-layer B prefetch ----------------
// Flat k-step counter S across layers; B-frag ring b[3][4], loads issued 2 steps
// ahead (incl. across the layer boundary into the NEXT layer's weights wpn).
// SB = (flat step base of this layer) % 3.  NFN/KTN describe the next layer.
template<int MFRAG, int NFRAG, int KT, int NFN, int KTN, int SB, bool RELU, bool TOPANEL>
__device__ __forceinline__ void layer_f(
    char* lds, const half8* __restrict__ wp, const half8* __restrict__ wpn,
    const float* __restrict__ bias, half8 (&b)[3][4],
    float* __restrict__ outf, const int* __restrict__ rowmap, int row0, int vend)
{
    const int t = threadIdx.x;
    const int lane = t & 63, wid = t >> 6;
    const int l15 = lane & 15, kb = lane >> 4;

    int baseA[MFRAG];
    #pragma unroll
    for (int m = 0; m < MFRAG; m++)
        baseA[m] = (((m * 16 + l15) * 1024) + kb * 16) ^ (((l15 >> 1) & 7) << 4);

    half8 a[2][MFRAG];
    #pragma unroll
    for (int m = 0; m < MFRAG; m++) a[0][m] = *(const half8*)(lds + baseA[m]);

    floatx4 acc[MFRAG][NFRAG] = {};

    #pragma unroll
    for (int kt = 0; kt < KT; kt++) {
        const int cur = kt & 1;
        if (kt + 1 < KT) {                         // A prefetch, 1 step ahead
            #pragma unroll
            for (int m = 0; m < MFRAG; m++)
                a[cur ^ 1][m] = *(const half8*)(lds + (baseA[m] ^ ((kt + 1) << 6)));
        }
        if (kt + 2 < KT) {                         // B prefetch, 2 steps ahead
            #pragma unroll
            for (int n = 0; n < NFRAG; n++)
                b[(SB + kt + 2) % 3][n] = wp[((wid * NFRAG + n) * KT + kt + 2) * 64 + lane];
        } else if constexpr (NFN > 0) {            // cross into next layer
            const int s2 = kt + 2 - KT;            // 0 or 1
            #pragma unroll
            for (int n = 0; n < NFN; n++)
                b[(SB + kt + 2) % 3][n] = wpn[((wid * NFN + n) * KTN + s2) * 64 + lane];
        }
        __builtin_amdgcn_s_setprio(1);
        #pragma unroll
        for (int m = 0; m < MFRAG; m++)
            #pragma unroll
            for (int n = 0; n < NFRAG; n++)
                acc[m][n] = __builtin_amdgcn_mfma_f32_16x16x32_f16(
                    a[cur][m], b[(SB + kt) % 3][n], acc[m][n], 0, 0, 0);
        __builtin_amdgcn_s_setprio(0);
    }

    __syncthreads();   // all waves done reading panel

    #pragma unroll
    for (int n = 0; n < NFRAG; n++) {
        const int col = wid * (NFRAG * 16) + n * 16 + l15;
        const float bb = bias[col];
        #pragma unroll
        for (int m = 0; m < MFRAG; m++) {
            #pragma unroll
            for (int e = 0; e < 4; e++) {
                const int row = m * 16 + kb * 4 + e;
                float v = acc[m][n][e] + bb;
                if constexpr (RELU) v = fmaxf(v, 0.0f);
                if constexpr (TOPANEL) {
                    *(f16*)(lds + pswz(row, col * 2)) = (f16)v;
                } else {
                    const int pr = row0 + row;
                    if (pr < vend) outf[(size_t)rowmap[pr] * SDIM_ + col] = v;
                }
            }
        }
    }
    if constexpr (TOPANEL) __syncthreads();   // panel is next layer's input
}

// ---------------- fused trunk: z -> 4 layers -> hT ----------------
__global__ __launch_bounds__(512, 2) void trunk_k(
    const float* __restrict__ z,
    const f16* __restrict__ W0p, const float* __restrict__ b0,
    const f16* __restrict__ W1p, const float* __restrict__ b1,
    const f16* __restrict__ W2p, const float* __restrict__ b2,
    const f16* __restrict__ W3p, const float* __restrict__ b3,
    f16* __restrict__ hT)
{
    extern __shared__ char lds[];
    const int t = threadIdx.x;
    const int row0 = blockIdx.x * 64;
    const int lane = t & 63, wid = t >> 6;

    const half8* w0 = (const half8*)W0p;
    const half8* w1 = (const half8*)W1p;
    const half8* w2 = (const half8*)W2p;
    const half8* w3 = (const half8*)W3p;

    half8 b[3][4];
    #pragma unroll
    for (int s = 0; s < 2; s++)                    // preload flat steps 0,1 (layer 0, KT=2)
        #pragma unroll
        for (int n = 0; n < 4; n++)
            b[s][n] = w0[((wid * 4 + n) * 2 + s) * 64 + lane];

    {   // fill panel with z rows (f32 -> f16), swizzled
        const int r = t >> 3, c = (t & 7) * 8;
        const float4 v0 = *(const float4*)(z + (size_t)(row0 + r) * NZ_ + c);
        const float4 v1 = *(const float4*)(z + (size_t)(row0 + r) * NZ_ + c + 4);
        half8 h = { (f16)v0.x, (f16)v0.y, (f16)v0.z, (f16)v0.w,
                    (f16)v1.x, (f16)v1.y, (f16)v1.z, (f16)v1.w };
        *(half8*)(lds + pswz(r, c * 2)) = h;
    }
    __syncthreads();

    // flat bases: 0, 2, 18, 34  ->  SB = 0, 2, 0, 1
    layer_f<4, 4, 2,  4, 16, 0, true, true>(lds, w0, w1, b0, b, nullptr, nullptr, 0, 0);
    layer_f<4, 4, 16, 4, 16, 2, true, true>(lds, w1, w2, b1, b, nullptr, nullptr, 0, 0);
    layer_f<4, 4, 16, 4, 16, 0, true, true>(lds, w2, w3, b2, b, nullptr, nullptr, 0, 0);
    layer_f<4, 4, 16, 0, 16, 1, true, true>(lds, w3, w3, b3, b, nullptr, nullptr, 0, 0);

    {   // coalesced panel -> hT
        const int r = t >> 3;
        #pragma unroll
        for (int p = 0; p < 8; p++) {
            const int c16 = (t & 7) + p * 8;
            half8 h = *(const half8*)(lds + pswz(r, c16 * 16));
            *(half8*)(hT + (size_t)(row0 + r) * H_ + c16 * 8) = h;
        }
    }
}

// ---------------- fused branches: gather -> 3 layers -> out scatter ----------------
// block (d + 8*i): XCD-pinned so each XCD streams one domain's weights.
__global__ __launch_bounds__(512, 2) void branch_k(
    const f16* __restrict__ hT,
    const f16* __restrict__ U1p, const float* __restrict__ c1,
    const f16* __restrict__ U2p, const float* __restrict__ c2,
    const f16* __restrict__ U3p, const float* __restrict__ c3,
    const f16* __restrict__ Uop, const float* __restrict__ co,
    const int* __restrict__ offs, const int* __restrict__ cnt,
    const int* __restrict__ rowmap, float* __restrict__ out)
{
    extern __shared__ char lds[];
    const int d = blockIdx.x & 7, i = blockIdx.x >> 3;
    const int c = cnt[d];
    if (i * 80 >= c) return;
    const int row0 = offs[d] + i * 80;
    const int vend = offs[d] + c;
    const int t = threadIdx.x;
    const int lane = t & 63, wid = t >> 6;

    const half8* u1 = (const half8*)(U1p + (size_t)d * H_ * H_);
    const half8* u2 = (const half8*)(U2p + (size_t)d * H_ * H_);
    const half8* u3 = (const half8*)(U3p + (size_t)d * H_ * H_);
    const half8* uo = (const half8*)(Uop + (size_t)d * H_ * SDIM_);

    half8 b[3][4];
    #pragma unroll
    for (int s = 0; s < 2; s++)                    // preload flat steps 0,1 (layer 1)
        #pragma unroll
        for (int n = 0; n < 4; n++)
            b[s][n] = u1[((wid * 4 + n) * 16 + s) * 64 + lane];

    // gather 80 trunk rows into swizzled panel (per-row fully coalesced)
    #pragma unroll
    for (int p = 0; p < 10; p++) {
        const int r   = p * 8 + (t >> 6);
        const int c16 = t & 63;
        const int src = rowmap[row0 + r];
        half8 h = *(const half8*)(hT + (size_t)src * H_ + c16 * 8);
        *(half8*)(lds + pswz(r, c16 * 16)) = h;
    }
    __syncthreads();

    // flat bases: 0, 16, 32, 48  ->  SB = 0, 1, 2, 0
    layer_f<5, 4, 16, 4, 16, 0, true,  true >(lds, u1, u2, c1 + d * H_,    b, nullptr, nullptr, 0, 0);
    layer_f<5, 4, 16, 4, 16, 1, true,  true >(lds, u2, u3, c2 + d * H_,    b, nullptr, nullptr, 0, 0);
    layer_f<5, 4, 16, 1, 16, 2, true,  true >(lds, u3, uo, c3 + d * H_,    b, nullptr, nullptr, 0, 0);
    layer_f<5, 1, 16, 0, 16, 0, false, false>(lds, uo, uo, co + d * SDIM_, b, out, rowmap, row0, vend);
}

// ---------------- host ----------------
extern "C" void kernel_launch(void* const* d_in, const int* in_sizes, int n_in,
                              void* d_out, int out_size, void* d_ws, size_t ws_size,
                              hipStream_t stream)
{
    const float* z  = (const float*)d_in[0];
    const int*   y  = (const int*)d_in[1];
    const float* W0 = (const float*)d_in[2];
    const float* b0 = (const float*)d_in[3];
    const float* W1 = (const float*)d_in[4];
    const float* b1 = (const float*)d_in[5];
    const float* W2 = (const float*)d_in[6];
    const float* b2 = (const float*)d_in[7];
    const float* W3 = (const float*)d_in[8];
    const float* b3 = (const float*)d_in[9];
    const float* U1 = (const float*)d_in[10];
    const float* c1 = (const float*)d_in[11];
    const float* U2 = (const float*)d_in[12];
    const float* c2 = (const float*)d_in[13];
    const float* U3 = (const float*)d_in[14];
    const float* c3 = (const float*)d_in[15];
    const float* Uo = (const float*)d_in[16];
    const float* co = (const float*)d_in[17];
    float* out = (float*)d_out;

    char* p = (char*)d_ws;
    auto take = [&](size_t nbytes) { char* r = p; p += (nbytes + 255) & ~(size_t)255; return r; };
    int* cnt     = (int*)take(ND_ * 4);
    int* offs    = (int*)take((ND_ + 1) * 4);
    int* running = (int*)take(ND_ * 4);
    int* rowmap  = (int*)take((size_t)(B_ + 128) * 4);
    f16* W0t = (f16*)take((size_t)H_ * NZ_ * 2);
    f16* W1t = (f16*)take((size_t)H_ * H_ * 2);
    f16* W2t = (f16*)take((size_t)H_ * H_ * 2);
    f16* W3t = (f16*)take((size_t)H_ * H_ * 2);
    f16* U1t = (f16*)take((size_t)ND_ * H_ * H_ * 2);
    f16* U2t = (f16*)take((size_t)ND_ * H_ * H_ * 2);
    f16* U3t = (f16*)take((size_t)ND_ * H_ * H_ * 2);
    f16* Uot = (f16*)take((size_t)ND_ * SDIM_ * H_ * 2);
    f16* hT  = (f16*)take((size_t)B_ * H_ * 2);

    hipFuncSetAttribute((const void*)trunk_k,  hipFuncAttributeMaxDynamicSharedMemorySize, 64 * 1024);
    hipFuncSetAttribute((const void*)branch_k, hipFuncAttributeMaxDynamicSharedMemorySize, 80 * 1024);

    misc_k   <<<dim3(1), dim3(256), 0, stream>>>(cnt, rowmap);
    count_k  <<<dim3(B_ / 256), dim3(256), 0, stream>>>(y, cnt);
    prefix_k <<<dim3(1), dim3(64), 0, stream>>>(cnt, offs, running);
    scatter_k<<<dim3(B_ / 256), dim3(256), 0, stream>>>(y, running, rowmap);

    tr_k<<<dim3(TR_BLOCKS), dim3(256), 0, stream>>>(W0, W1, W2, W3, U1, U2, U3, Uo,
                                                    W0t, W1t, W2t, W3t, U1t, U2t, U3t, Uot);

    trunk_k<<<dim3(B_ / 64), dim3(512), 64 * 1024, stream>>>(
        z, W0t, b0, W1t, b1, W2t, b2, W3t, b3, hT);

    branch_k<<<dim3(8 * 41), dim3(512), 80 * 1024, stream>>>(
        hT, U1t, c1, U2t, c2, U3t, c3, Uot, co, offs, cnt, rowmap, out);
}